// Round 1
// baseline (339.768 us; speedup 1.0000x reference)
//
#include <hip/hip_runtime.h>

#define NUM_EMB 1024
#define EMB_DIM 256
#define NPIX    32768      // 32 * 32 * 32
#define HW      1024       // 32*32 spatial per batch
#define ZQ_ELEMS 8388608   // 32*256*32*32

// ws layout (bytes):
//   [0..8)            double loss_accum
//   [8..8+4096)       float  tnorm[1024]
//   [8+4096.. +128KB) int    idx[32768]

// ---- numpy pairwise_sum replica over 128 squared terms, stride between terms ----
// numpy: r[0..7]=a[0..7]; for i=8..120 step 8: r[j]+=a[i+j];
//        res=((r0+r1)+(r2+r3))+((r4+r5)+(r6+r7))
// terms are individually rounded squares (z**2 temp array), so __fmul_rn + __fadd_rn,
// no FMA contraction allowed.
__device__ __forceinline__ float pw128_sq(const float* x, int stride) {
  float r[8];
#pragma unroll
  for (int j = 0; j < 8; ++j) {
    float v = x[j * stride];
    r[j] = __fmul_rn(v, v);
  }
  for (int i = 8; i < 128; i += 8) {
#pragma unroll
    for (int j = 0; j < 8; ++j) {
      float v = x[(i + j) * stride];
      r[j] = __fadd_rn(r[j], __fmul_rn(v, v));
    }
  }
  float s01 = __fadd_rn(r[0], r[1]);
  float s23 = __fadd_rn(r[2], r[3]);
  float s45 = __fadd_rn(r[4], r[5]);
  float s67 = __fadd_rn(r[6], r[7]);
  return __fadd_rn(__fadd_rn(s01, s23), __fadd_rn(s45, s67));
}

// ---- kernel 1: codebook norms t_k, also zero the loss accumulator ----
__global__ void vq_norms_kernel(const float* __restrict__ emb,
                                float* __restrict__ tnorm,
                                double* __restrict__ loss_accum) {
  int k = blockIdx.x * blockDim.x + threadIdx.x;
  if (k == 0) *loss_accum = 0.0;
  if (k < NUM_EMB) {
    const float* row = emb + (size_t)k * EMB_DIM;
    // n=256 > 128 -> numpy splits into two 128 blocks, then one add
    tnorm[k] = __fadd_rn(pw128_sq(row, 1), pw128_sq(row + 128, 1));
  }
}

// ---- kernel 2: fused GEMM + argmin ----
// block = 256 threads (16x16), 64 pixels x all 1024 codes, K=256 in 64-chunks.
__global__ __launch_bounds__(256) void vq_main_kernel(
    const float* __restrict__ z, const float* __restrict__ emb,
    const float* __restrict__ tnorm, int* __restrict__ idx_out,
    float* __restrict__ idx_f_out) {
  __shared__ float zs[256][64];   // [c][pixel] 64 KB
  __shared__ float es[64][64];    // [k][code]  16 KB (code index XOR-swizzled by ((k&15)<<2))

  const int t  = threadIdx.x;
  const int tx = t & 15;          // code group (4 codes)
  const int ty = t >> 4;          // pixel group (4 pixels)
  const int n0 = blockIdx.x * 64; // first pixel of this block (always within one batch b)
  const int b  = n0 >> 10;
  const int hw = n0 & 1023;
  const float* zbase = z + (size_t)b * (EMB_DIM * HW) + hw;

  // ---- stage z tile: zs[c][m], coalesced float4 over pixels ----
  {
    const int m4 = (t & 15) * 4;
    const int c0 = t >> 4;
    for (int cc = 0; cc < 256; cc += 16) {
      const int c = cc + c0;
      const float4 v = *(const float4*)(zbase + (size_t)c * HW + m4);
      *(float4*)&zs[c][m4] = v;
    }
  }
  __syncthreads();

  // ---- s_n = numpy-pairwise sum of z^2 per pixel, stash in es (not yet used) ----
  float* stash = &es[0][0];
  if (t < 64) {
    stash[t] = __fadd_rn(pw128_sq(&zs[0][t], 64), pw128_sq(&zs[128][t], 64));
  }
  __syncthreads();
  float sreg[4];
#pragma unroll
  for (int i = 0; i < 4; ++i) sreg[i] = stash[ty * 4 + i];
  __syncthreads();

  float bestv[4];
  int   besti[4];
#pragma unroll
  for (int i = 0; i < 4; ++i) { bestv[i] = 3.4e38f; besti[i] = 0; }

  for (int nt_ = 0; nt_ < NUM_EMB; nt_ += 64) {
    float acc[4][4];
#pragma unroll
    for (int i = 0; i < 4; ++i)
#pragma unroll
      for (int j = 0; j < 4; ++j) acc[i][j] = 0.0f;

    for (int kt = 0; kt < EMB_DIM; kt += 64) {
      // stage e tile transposed: es[k][n], coalesced float4 along k from emb
      {
        const int k4 = (t & 15) * 4;
        const int nb = t >> 4;
#pragma unroll
        for (int p = 0; p < 4; ++p) {
          const int n_ = nb + p * 16;
          const float4 v = *(const float4*)(emb + (size_t)(nt_ + n_) * EMB_DIM + kt + k4);
          es[k4 + 0][n_ ^ (((k4 + 0) & 15) << 2)] = v.x;
          es[k4 + 1][n_ ^ (((k4 + 1) & 15) << 2)] = v.y;
          es[k4 + 2][n_ ^ (((k4 + 2) & 15) << 2)] = v.z;
          es[k4 + 3][n_ ^ (((k4 + 3) & 15) << 2)] = v.w;
        }
      }
      __syncthreads();
#pragma unroll 8
      for (int k = 0; k < 64; ++k) {
        const float4 av = *(const float4*)&zs[kt + k][ty * 4];
        const float4 bv = *(const float4*)&es[k][(tx * 4) ^ ((k & 15) << 2)];
        const float a_[4] = {av.x, av.y, av.z, av.w};
        const float b_[4] = {bv.x, bv.y, bv.z, bv.w};
#pragma unroll
        for (int i = 0; i < 4; ++i)
#pragma unroll
          for (int j = 0; j < 4; ++j) acc[i][j] += a_[i] * b_[j];  // FMA ok here
      }
      __syncthreads();
    }

    // ---- epilogue: d = fl(fl(s+t) - 2m), running argmin (indices ascending) ----
    const int kbase = nt_ + tx * 4;
    const float4 tk4 = *(const float4*)&tnorm[kbase];
    const float tk_[4] = {tk4.x, tk4.y, tk4.z, tk4.w};
#pragma unroll
    for (int i = 0; i < 4; ++i) {
#pragma unroll
      for (int j = 0; j < 4; ++j) {
        const float a = __fadd_rn(sreg[i], tk_[j]);
        const float d = __fsub_rn(a, 2.0f * acc[i][j]);  // 2*m exact; one rounding
        if (d < bestv[i]) { bestv[i] = d; besti[i] = kbase + j; }
      }
    }
  }

  // ---- cross-thread reduction per pixel (lexicographic: min val, then min idx) ----
  float* rv = &es[0][0];            // 1024 floats
  int*   ri = (int*)&es[16][0];     // next 1024 slots
#pragma unroll
  for (int i = 0; i < 4; ++i) {
    const int m = ty * 4 + i;
    rv[m * 16 + tx] = bestv[i];
    ri[m * 16 + tx] = besti[i];
  }
  __syncthreads();
  if (t < 64) {
    float bv = rv[t * 16];
    int   bi = ri[t * 16];
    for (int x = 1; x < 16; ++x) {
      const float v  = rv[t * 16 + x];
      const int   ii = ri[t * 16 + x];
      if (v < bv || (v == bv && ii < bi)) { bv = v; bi = ii; }
    }
    idx_out[n0 + t]   = bi;
    idx_f_out[n0 + t] = (float)bi;  // output dtype is f32
  }
}

// ---- kernel 3: z_q gather + straight-through + loss partial sums ----
__global__ __launch_bounds__(256) void vq_outputs_kernel(
    const float* __restrict__ z, const float* __restrict__ emb,
    const int* __restrict__ idx_in, float* __restrict__ out,
    double* __restrict__ loss_accum) {
  const int t  = threadIdx.x;
  const int n0 = blockIdx.x * 64;
  const int m  = t & 63;
  const int c0 = t >> 6;
  const int b  = n0 >> 10;
  const int hw = n0 & 1023;
  const float* zb = z   + (size_t)b * (EMB_DIM * HW) + hw + m;
  float*       ob = out + (size_t)b * (EMB_DIM * HW) + hw + m;
  const int idx = idx_in[n0 + m];
  const float* er = emb + (size_t)idx * EMB_DIM;

  double lsum = 0.0;
  for (int c = c0; c < EMB_DIM; c += 4) {
    const float e  = er[c];
    const float zv = zb[(size_t)c * HW];
    const float diff = e - zv;       // fl(z_q - z)
    const float zq   = zv + diff;    // straight-through: fl(z + fl(z_q - z))
    ob[(size_t)c * HW] = zq;
    lsum += (double)diff * (double)diff;
  }

  __shared__ double red[256];
  red[t] = lsum;
  __syncthreads();
  for (int s2 = 128; s2 > 0; s2 >>= 1) {
    if (t < s2) red[t] += red[t + s2];
    __syncthreads();
  }
  if (t == 0) atomicAdd(loss_accum, red[0]);
}

// ---- kernel 4: finalize loss: L_e + 0.25*L_q, both equal mean((zq-z)^2) ----
__global__ void vq_finalize_kernel(const double* __restrict__ loss_accum,
                                   float* __restrict__ out_loss) {
  const float L = (float)(*loss_accum / (double)ZQ_ELEMS);
  out_loss[0] = __fadd_rn(L, __fmul_rn(0.25f, L));
}

extern "C" void kernel_launch(void* const* d_in, const int* in_sizes, int n_in,
                              void* d_out, int out_size, void* d_ws, size_t ws_size,
                              hipStream_t stream) {
  const float* z   = (const float*)d_in[0];   // (32, 256, 32, 32) f32
  const float* emb = (const float*)d_in[1];   // (1024, 256) f32

  float* out        = (float*)d_out;          // [0..8388608): z_q_out (B,C,H,W)
  float* out_loss   = out + ZQ_ELEMS;         // [8388608]: vq_loss
  float* out_idx_f  = out + ZQ_ELEMS + 1;     // [8388609..): encoding_indices as f32

  double* loss_accum = (double*)d_ws;
  float*  tnorm      = (float*)((char*)d_ws + 8);
  int*    idxbuf     = (int*)((char*)d_ws + 8 + 4096);

  vq_norms_kernel<<<4, 256, 0, stream>>>(emb, tnorm, loss_accum);
  vq_main_kernel<<<NPIX / 64, 256, 0, stream>>>(z, emb, tnorm, idxbuf, out_idx_f);
  vq_outputs_kernel<<<NPIX / 64, 256, 0, stream>>>(z, emb, idxbuf, out, loss_accum);
  vq_finalize_kernel<<<1, 1, 0, stream>>>(loss_accum, out_loss);
}

// Round 2
// 310.983 us; speedup vs baseline: 1.0926x; 1.0926x over previous
//
#include <hip/hip_runtime.h>

#define NUM_EMB 1024
#define EMB_DIM 256
#define NPIX    32768      // 32 * 32 * 32
#define HW      1024       // 32*32 spatial per batch
#define ZQ_ELEMS 8388608   // 32*256*32*32

// ws layout (bytes):
//   [0..8)                 double loss_accum
//   [8..8+4096)            float  tnorm[1024]
//   [8192..8192+131072)    float  snorm[32768]
//   [139264..139264+262144) u64   keys[32768]  (argmin: (d_bits<<32)|idx)
#define WS_TNORM 8
#define WS_SNORM 8192
#define WS_KEYS  139264

// ---- numpy pairwise_sum replica over 128 squared terms, stride between terms ----
__device__ __forceinline__ float pw128_sq(const float* x, int stride) {
  float r[8];
#pragma unroll
  for (int j = 0; j < 8; ++j) {
    float v = x[(size_t)j * stride];
    r[j] = __fmul_rn(v, v);
  }
  for (int i = 8; i < 128; i += 8) {
#pragma unroll
    for (int j = 0; j < 8; ++j) {
      float v = x[(size_t)(i + j) * stride];
      r[j] = __fadd_rn(r[j], __fmul_rn(v, v));
    }
  }
  float s01 = __fadd_rn(r[0], r[1]);
  float s23 = __fadd_rn(r[2], r[3]);
  float s45 = __fadd_rn(r[4], r[5]);
  float s67 = __fadd_rn(r[6], r[7]);
  return __fadd_rn(__fadd_rn(s01, s23), __fadd_rn(s45, s67));
}

// ---- init: keys = max, loss = 0 ----
__global__ void vq_init_kernel(unsigned long long* __restrict__ keys,
                               double* __restrict__ loss_accum) {
  int i = blockIdx.x * blockDim.x + threadIdx.x;
  if (i == 0) *loss_accum = 0.0;
  if (i < NPIX) keys[i] = ~0ull;
}

// ---- codebook norms t_k ----
__global__ void vq_norms_kernel(const float* __restrict__ emb,
                                float* __restrict__ tnorm) {
  int k = blockIdx.x * blockDim.x + threadIdx.x;
  if (k < NUM_EMB) {
    const float* row = emb + (size_t)k * EMB_DIM;
    tnorm[k] = __fadd_rn(pw128_sq(row, 1), pw128_sq(row + 128, 1));
  }
}

// ---- pixel norms s_n (coalesced: lane-adjacent pixels, loop over c) ----
__global__ void vq_snorm_kernel(const float* __restrict__ z,
                                float* __restrict__ snorm) {
  int n = blockIdx.x * blockDim.x + threadIdx.x;  // pixel
  if (n < NPIX) {
    const int b = n >> 10, hw = n & 1023;
    const float* base = z + (size_t)b * (EMB_DIM * HW) + hw;
    snorm[n] = __fadd_rn(pw128_sq(base, HW), pw128_sq(base + (size_t)128 * HW, HW));
  }
}

// ---- main: 128 pixels x 128 codes per block, 8x8 micro-tile, atomicMin argmin ----
// grid 2048: pt = bid>>3 (256 pixel tiles), nt = bid&7 (8 code tiles)
__global__ __launch_bounds__(256) void vq_main_kernel(
    const float* __restrict__ z, const float* __restrict__ emb,
    const float* __restrict__ tnorm, const float* __restrict__ snorm,
    unsigned long long* __restrict__ keys) {
  __shared__ float zs[32][128];   // [k][pixel] 16 KB
  __shared__ float es[32][128];   // [k][phys-code] 16 KB, half-split layout:
                                  // logical code n -> phys ((n&4)<<4) + ((n>>3)<<2) + (n&3)

  const int t   = threadIdx.x;
  const int bid = blockIdx.x;
  const int pt  = bid >> 3;
  const int nt  = bid & 7;
  const int m0  = pt * 128;        // pixel base (within one batch: 1024 % 128 == 0)
  const int n0  = nt * 128;        // code base
  const int b   = m0 >> 10;
  const int hw  = m0 & 1023;
  const float* zbase = z + (size_t)b * (EMB_DIM * HW) + hw;

  const int tx = t & 15, ty = t >> 4;

  // staging indices
  const int sm  = (t & 31) * 4;    // pixel quad (z stage)
  const int sk  = t >> 5;          // k row base 0..7 (z stage)
  const int en  = t & 127;         // code (e stage)
  const int ek0 = (t >> 7) * 16;   // k half base (e stage)
  // phys column for this thread's staged code
  const int pcol = ((en & 4) << 4) + ((en >> 3) << 2) + (en & 3);
  const float* erow = emb + (size_t)(n0 + en) * EMB_DIM;

  float acc[8][8] = {};

  for (int kt = 0; kt < EMB_DIM; kt += 32) {
    // stage z tile: zs[k][m], float4 coalesced over pixels
#pragma unroll
    for (int r = 0; r < 4; ++r) {
      const int k = sk + r * 8;
      const float4 v = *(const float4*)(zbase + (size_t)(kt + k) * HW + sm);
      *(float4*)&zs[k][sm] = v;
    }
    // stage e tile transposed into half-split layout
#pragma unroll
    for (int r = 0; r < 4; ++r) {
      const int k4 = ek0 + r * 4;
      const float4 v = *(const float4*)(erow + kt + k4);
      es[k4 + 0][pcol] = v.x;
      es[k4 + 1][pcol] = v.y;
      es[k4 + 2][pcol] = v.z;
      es[k4 + 3][pcol] = v.w;
    }
    __syncthreads();

#pragma unroll 4
    for (int k = 0; k < 32; ++k) {
      const float4 a0 = *(const float4*)&zs[k][ty * 8];
      const float4 a1 = *(const float4*)&zs[k][ty * 8 + 4];
      const float4 b0 = *(const float4*)&es[k][tx * 4];        // codes tx*8+0..3
      const float4 b1 = *(const float4*)&es[k][64 + tx * 4];   // codes tx*8+4..7
      const float a_[8] = {a0.x, a0.y, a0.z, a0.w, a1.x, a1.y, a1.z, a1.w};
      const float b_[8] = {b0.x, b0.y, b0.z, b0.w, b1.x, b1.y, b1.z, b1.w};
#pragma unroll
      for (int i = 0; i < 8; ++i)
#pragma unroll
        for (int j = 0; j < 8; ++j) acc[i][j] += a_[i] * b_[j];
    }
    __syncthreads();
  }

  // ---- epilogue: d = fl(fl(s+t) - 2m), per-thread argmin over 8 codes ----
  float s_[8], t_[8];
#pragma unroll
  for (int i = 0; i < 8; ++i) s_[i] = snorm[m0 + ty * 8 + i];
#pragma unroll
  for (int j = 0; j < 8; ++j) t_[j] = tnorm[n0 + tx * 8 + j];

  float bestv[8];
  int   besti[8];
#pragma unroll
  for (int i = 0; i < 8; ++i) {
    bestv[i] = 3.4e38f;
    besti[i] = 0;
#pragma unroll
    for (int j = 0; j < 8; ++j) {
      const float a = __fadd_rn(s_[i], t_[j]);
      const float d = __fsub_rn(a, 2.0f * acc[i][j]);
      if (d < bestv[i]) { bestv[i] = d; besti[i] = n0 + tx * 8 + j; }
    }
  }

  // ---- cross-tx reduction (16 threads share each pixel), padded stride 17 ----
  float* rv = &zs[0][0];            // 128*17 floats = 8704 <= 4096? NO -> use both arrays
  int*   ri = (int*)&es[0][0];
#pragma unroll
  for (int i = 0; i < 8; ++i) {
    const int p = ty * 8 + i;
    rv[p * 17 + tx] = bestv[i];
    ri[p * 17 + tx] = besti[i];
  }
  __syncthreads();
  if (t < 128) {
    float bv = rv[t * 17];
    int   bi = ri[t * 17];
#pragma unroll
    for (int x = 1; x < 16; ++x) {
      const float v  = rv[t * 17 + x];
      const int   ii = ri[t * 17 + x];
      if (v < bv || (v == bv && ii < bi)) { bv = v; bi = ii; }
    }
    const unsigned long long key =
        ((unsigned long long)__float_as_uint(bv) << 32) | (unsigned)bi;
    atomicMin(&keys[m0 + t], key);
  }
}

// ---- outputs: z_q gather + straight-through + loss partials + idx as f32 ----
__global__ __launch_bounds__(256) void vq_outputs_kernel(
    const float* __restrict__ z, const float* __restrict__ emb,
    const unsigned long long* __restrict__ keys, float* __restrict__ out,
    float* __restrict__ out_idx_f, double* __restrict__ loss_accum) {
  const int t  = threadIdx.x;
  const int n0 = blockIdx.x * 64;
  const int m  = t & 63;
  const int c0 = t >> 6;
  const int b  = n0 >> 10;
  const int hw = n0 & 1023;
  const float* zb = z   + (size_t)b * (EMB_DIM * HW) + hw + m;
  float*       ob = out + (size_t)b * (EMB_DIM * HW) + hw + m;
  const int idx = (int)(unsigned)(keys[n0 + m] & 0xffffffffu);
  const float* er = emb + (size_t)idx * EMB_DIM;
  if (c0 == 0) out_idx_f[n0 + m] = (float)idx;

  double lsum = 0.0;
  for (int c = c0; c < EMB_DIM; c += 4) {
    const float e  = er[c];
    const float zv = zb[(size_t)c * HW];
    const float diff = e - zv;       // fl(z_q - z)
    const float zq   = zv + diff;    // straight-through: fl(z + fl(z_q - z))
    ob[(size_t)c * HW] = zq;
    lsum += (double)diff * (double)diff;
  }

  __shared__ double red[256];
  red[t] = lsum;
  __syncthreads();
  for (int s2 = 128; s2 > 0; s2 >>= 1) {
    if (t < s2) red[t] += red[t + s2];
    __syncthreads();
  }
  if (t == 0) atomicAdd(loss_accum, red[0]);
}

__global__ void vq_finalize_kernel(const double* __restrict__ loss_accum,
                                   float* __restrict__ out_loss) {
  const float L = (float)(*loss_accum / (double)ZQ_ELEMS);
  out_loss[0] = __fadd_rn(L, __fmul_rn(0.25f, L));
}

extern "C" void kernel_launch(void* const* d_in, const int* in_sizes, int n_in,
                              void* d_out, int out_size, void* d_ws, size_t ws_size,
                              hipStream_t stream) {
  const float* z   = (const float*)d_in[0];   // (32, 256, 32, 32) f32
  const float* emb = (const float*)d_in[1];   // (1024, 256) f32

  float* out       = (float*)d_out;           // z_q_out (B,C,H,W)
  float* out_loss  = out + ZQ_ELEMS;          // vq_loss scalar
  float* out_idx_f = out + ZQ_ELEMS + 1;      // encoding_indices as f32

  double* loss_accum = (double*)d_ws;
  float*  tnorm = (float*)((char*)d_ws + WS_TNORM);
  float*  snorm = (float*)((char*)d_ws + WS_SNORM);
  unsigned long long* keys = (unsigned long long*)((char*)d_ws + WS_KEYS);

  vq_init_kernel<<<NPIX / 256, 256, 0, stream>>>(keys, loss_accum);
  vq_norms_kernel<<<4, 256, 0, stream>>>(emb, tnorm);
  vq_snorm_kernel<<<NPIX / 256, 256, 0, stream>>>(z, snorm);
  vq_main_kernel<<<2048, 256, 0, stream>>>(z, emb, tnorm, snorm, keys);
  vq_outputs_kernel<<<NPIX / 64, 256, 0, stream>>>(z, emb, keys, out, out_idx_f,
                                                   loss_accum);
  vq_finalize_kernel<<<1, 1, 0, stream>>>(loss_accum, out_loss);
}

// Round 3
// 300.033 us; speedup vs baseline: 1.1324x; 1.0365x over previous
//
#include <hip/hip_runtime.h>

#define NUM_EMB 1024
#define EMB_DIM 256
#define NPIX    32768      // 32 * 32 * 32
#define HW      1024       // 32*32 spatial per batch
#define ZQ_ELEMS 8388608   // 32*256*32*32

// ws layout (bytes):
//   [0..8)                  double loss_accum
//   [8..8+4096)             float  tnorm[1024]
//   [8192..8192+131072)     float  snorm[32768]
//   [139264..139264+262144) u64   keys[32768]  (argmin: (d_bits<<32)|idx)
#define WS_TNORM 8
#define WS_SNORM 8192
#define WS_KEYS  139264

// ---- numpy pairwise_sum replica over 128 squared terms, stride between terms ----
__device__ __forceinline__ float pw128_sq(const float* x, int stride) {
  float r[8];
#pragma unroll
  for (int j = 0; j < 8; ++j) {
    float v = x[(size_t)j * stride];
    r[j] = __fmul_rn(v, v);
  }
  for (int i = 8; i < 128; i += 8) {
#pragma unroll
    for (int j = 0; j < 8; ++j) {
      float v = x[(size_t)(i + j) * stride];
      r[j] = __fadd_rn(r[j], __fmul_rn(v, v));
    }
  }
  float s01 = __fadd_rn(r[0], r[1]);
  float s23 = __fadd_rn(r[2], r[3]);
  float s45 = __fadd_rn(r[4], r[5]);
  float s67 = __fadd_rn(r[6], r[7]);
  return __fadd_rn(__fadd_rn(s01, s23), __fadd_rn(s45, s67));
}

// ---- prep: keys=~0, loss=0, snorm (blocks 0..127), tnorm (blocks 128..131) ----
__global__ __launch_bounds__(256) void vq_prep_kernel(
    const float* __restrict__ z, const float* __restrict__ emb,
    float* __restrict__ tnorm, float* __restrict__ snorm,
    unsigned long long* __restrict__ keys, double* __restrict__ loss_accum) {
  const int gid = blockIdx.x * 256 + threadIdx.x;
  if (gid == 0) *loss_accum = 0.0;
  if (gid < NPIX) {
    keys[gid] = ~0ull;
    const int b = gid >> 10, hw = gid & 1023;
    const float* base = z + (size_t)b * (EMB_DIM * HW) + hw;
    snorm[gid] = __fadd_rn(pw128_sq(base, HW), pw128_sq(base + (size_t)128 * HW, HW));
  } else {
    const int k = gid - NPIX;
    if (k < NUM_EMB) {
      const float* row = emb + (size_t)k * EMB_DIM;
      tnorm[k] = __fadd_rn(pw128_sq(row, 1), pw128_sq(row + 128, 1));
    }
  }
}

// ---- main: 128 px x 128 codes per block, 8x8 micro-tile, dbuf LDS + T14 ----
// logical bid: pt = bid>>3 (256 pixel tiles), nt = bid&7 (8 code tiles)
// XCD swizzle: hw bid h -> logical (h&7)*256 + (h>>3): each XCD owns 32 pixel tiles.
__global__ __launch_bounds__(256) void vq_main_kernel(
    const float* __restrict__ z, const float* __restrict__ emb,
    const float* __restrict__ tnorm, const float* __restrict__ snorm,
    unsigned long long* __restrict__ keys) {
  __shared__ float zs[2][32][128];   // [buf][k][pixel] 2x16 KB
  __shared__ float es[2][32][128];   // [buf][k][phys-code] 2x16 KB, half-split:
                                     // code n -> phys ((n&4)<<4)+((n>>3)<<2)+(n&3)

  const int t  = threadIdx.x;
  const int hb = blockIdx.x;
  const int bid = (hb & 7) * 256 + (hb >> 3);
  const int pt = bid >> 3;
  const int nt = bid & 7;
  const int m0 = pt * 128;
  const int n0 = nt * 128;
  const int b  = m0 >> 10;
  const int hw = m0 & 1023;
  const float* zbase = z + (size_t)b * (EMB_DIM * HW) + hw;

  const int tx = t & 15, ty = t >> 4;

  // staging indices
  const int zrow = t >> 5;          // k row base 0..7
  const int zcol = (t & 31) * 4;    // pixel quad
  const int en   = t & 127;         // code
  const int ek0  = (t >> 7) * 16;   // k half base
  const int pcol = ((en & 4) << 4) + ((en >> 3) << 2) + (en & 3);
  const float* erow = emb + (size_t)(n0 + en) * EMB_DIM;

  float acc[8][8] = {};
  float4 zl[4], el[4];

  // ---- prologue: load + write tile kt=0 into buf 0 ----
#pragma unroll
  for (int r = 0; r < 4; ++r)
    zl[r] = *(const float4*)(zbase + (size_t)(zrow + r * 8) * HW + zcol);
#pragma unroll
  for (int r = 0; r < 4; ++r)
    el[r] = *(const float4*)(erow + ek0 + r * 4);
#pragma unroll
  for (int r = 0; r < 4; ++r)
    *(float4*)&zs[0][zrow + r * 8][zcol] = zl[r];
#pragma unroll
  for (int r = 0; r < 4; ++r) {
    const int k4 = ek0 + r * 4;
    es[0][k4 + 0][pcol] = el[r].x;
    es[0][k4 + 1][pcol] = el[r].y;
    es[0][k4 + 2][pcol] = el[r].z;
    es[0][k4 + 3][pcol] = el[r].w;
  }
  __syncthreads();

  int cur = 0;
  for (int kt = 0; kt < 8; ++kt) {
    // early-issue next tile's global loads (latency hides under compute)
    if (kt < 7) {
      const int kb = (kt + 1) * 32;
#pragma unroll
      for (int r = 0; r < 4; ++r)
        zl[r] = *(const float4*)(zbase + (size_t)(kb + zrow + r * 8) * HW + zcol);
#pragma unroll
      for (int r = 0; r < 4; ++r)
        el[r] = *(const float4*)(erow + kb + ek0 + r * 4);
    }

#pragma unroll 4
    for (int k = 0; k < 32; ++k) {
      const float4 a0 = *(const float4*)&zs[cur][k][ty * 8];
      const float4 a1 = *(const float4*)&zs[cur][k][ty * 8 + 4];
      const float4 b0 = *(const float4*)&es[cur][k][tx * 4];       // codes +0..3
      const float4 b1 = *(const float4*)&es[cur][k][64 + tx * 4];  // codes +4..7
      const float a_[8] = {a0.x, a0.y, a0.z, a0.w, a1.x, a1.y, a1.z, a1.w};
      const float b_[8] = {b0.x, b0.y, b0.z, b0.w, b1.x, b1.y, b1.z, b1.w};
#pragma unroll
      for (int i = 0; i < 8; ++i)
#pragma unroll
        for (int j = 0; j < 8; ++j) acc[i][j] += a_[i] * b_[j];
    }

    if (kt < 7) {
      const int nb = cur ^ 1;
#pragma unroll
      for (int r = 0; r < 4; ++r)
        *(float4*)&zs[nb][zrow + r * 8][zcol] = zl[r];
#pragma unroll
      for (int r = 0; r < 4; ++r) {
        const int k4 = ek0 + r * 4;
        es[nb][k4 + 0][pcol] = el[r].x;
        es[nb][k4 + 1][pcol] = el[r].y;
        es[nb][k4 + 2][pcol] = el[r].z;
        es[nb][k4 + 3][pcol] = el[r].w;
      }
      __syncthreads();
      cur = nb;
    }
  }

  // ---- epilogue: d = fl(fl(s+t) - 2m), per-thread argmin over 8 codes ----
  float s_[8], t_[8];
#pragma unroll
  for (int i = 0; i < 8; ++i) s_[i] = snorm[m0 + ty * 8 + i];
#pragma unroll
  for (int j = 0; j < 8; ++j) t_[j] = tnorm[n0 + tx * 8 + j];

  float bestv[8];
  int   besti[8];
#pragma unroll
  for (int i = 0; i < 8; ++i) {
    bestv[i] = 3.4e38f;
    besti[i] = 0;
#pragma unroll
    for (int j = 0; j < 8; ++j) {
      const float a = __fadd_rn(s_[i], t_[j]);
      const float d = __fsub_rn(a, 2.0f * acc[i][j]);
      if (d < bestv[i]) { bestv[i] = d; besti[i] = n0 + tx * 8 + j; }
    }
  }

  __syncthreads();  // all compute reads done; safe to reuse LDS

  // ---- cross-tx reduction (16 threads share each pixel), padded stride 17 ----
  float* rv = &zs[0][0][0];
  int*   ri = (int*)&es[0][0][0];
#pragma unroll
  for (int i = 0; i < 8; ++i) {
    const int p = ty * 8 + i;
    rv[p * 17 + tx] = bestv[i];
    ri[p * 17 + tx] = besti[i];
  }
  __syncthreads();
  if (t < 128) {
    float bv = rv[t * 17];
    int   bi = ri[t * 17];
#pragma unroll
    for (int x = 1; x < 16; ++x) {
      const float v  = rv[t * 17 + x];
      const int   ii = ri[t * 17 + x];
      if (v < bv || (v == bv && ii < bi)) { bv = v; bi = ii; }
    }
    const unsigned long long key =
        ((unsigned long long)__float_as_uint(bv) << 32) | (unsigned)bi;
    atomicMin(&keys[m0 + t], key);
  }
}

// ---- outputs: z_q gather + straight-through + loss partials + idx as f32 ----
__global__ __launch_bounds__(256) void vq_outputs_kernel(
    const float* __restrict__ z, const float* __restrict__ emb,
    const unsigned long long* __restrict__ keys, float* __restrict__ out,
    float* __restrict__ out_idx_f, double* __restrict__ loss_accum) {
  const int t  = threadIdx.x;
  const int n0 = blockIdx.x * 64;
  const int m  = t & 63;
  const int c0 = t >> 6;
  const int b  = n0 >> 10;
  const int hw = n0 & 1023;
  const float* zb = z   + (size_t)b * (EMB_DIM * HW) + hw + m;
  float*       ob = out + (size_t)b * (EMB_DIM * HW) + hw + m;
  const int idx = (int)(unsigned)(keys[n0 + m] & 0xffffffffu);
  const float* er = emb + (size_t)idx * EMB_DIM;
  if (c0 == 0) out_idx_f[n0 + m] = (float)idx;

  double lsum = 0.0;
  for (int c = c0; c < EMB_DIM; c += 4) {
    const float e  = er[c];
    const float zv = zb[(size_t)c * HW];
    const float diff = e - zv;       // fl(z_q - z)
    const float zq   = zv + diff;    // straight-through: fl(z + fl(z_q - z))
    ob[(size_t)c * HW] = zq;
    lsum += (double)diff * (double)diff;
  }

  __shared__ double red[256];
  red[t] = lsum;
  __syncthreads();
  for (int s2 = 128; s2 > 0; s2 >>= 1) {
    if (t < s2) red[t] += red[t + s2];
    __syncthreads();
  }
  if (t == 0) atomicAdd(loss_accum, red[0]);
}

__global__ void vq_finalize_kernel(const double* __restrict__ loss_accum,
                                   float* __restrict__ out_loss) {
  const float L = (float)(*loss_accum / (double)ZQ_ELEMS);
  out_loss[0] = __fadd_rn(L, __fmul_rn(0.25f, L));
}

extern "C" void kernel_launch(void* const* d_in, const int* in_sizes, int n_in,
                              void* d_out, int out_size, void* d_ws, size_t ws_size,
                              hipStream_t stream) {
  const float* z   = (const float*)d_in[0];   // (32, 256, 32, 32) f32
  const float* emb = (const float*)d_in[1];   // (1024, 256) f32

  float* out       = (float*)d_out;           // z_q_out (B,C,H,W)
  float* out_loss  = out + ZQ_ELEMS;          // vq_loss scalar
  float* out_idx_f = out + ZQ_ELEMS + 1;      // encoding_indices as f32

  double* loss_accum = (double*)d_ws;
  float*  tnorm = (float*)((char*)d_ws + WS_TNORM);
  float*  snorm = (float*)((char*)d_ws + WS_SNORM);
  unsigned long long* keys = (unsigned long long*)((char*)d_ws + WS_KEYS);

  vq_prep_kernel<<<132, 256, 0, stream>>>(z, emb, tnorm, snorm, keys, loss_accum);
  vq_main_kernel<<<2048, 256, 0, stream>>>(z, emb, tnorm, snorm, keys);
  vq_outputs_kernel<<<NPIX / 64, 256, 0, stream>>>(z, emb, keys, out, out_idx_f,
                                                   loss_accum);
  vq_finalize_kernel<<<1, 1, 0, stream>>>(loss_accum, out_loss);
}